// Round 1
// baseline (1767.275 us; speedup 1.0000x reference)
//
#include <hip/hip_runtime.h>
#include <cmath>

#define BB 2
#define LL 2048
#define DD 1024
#define HH 16
#define HDD 64

// ---------------------------------------------------------------------------
// GEMM: C[M,N] = A[M,K] @ W[N,K]^T + bias[N] (+ res[M,N])
// 64x64 tile, BK=16, 256 threads, 4x4 micro-tile. fp32 baseline.
// ---------------------------------------------------------------------------
template <bool ADD_RES>
__global__ __launch_bounds__(256) void gemm_bt(
    const float* __restrict__ A, const float* __restrict__ W,
    const float* __restrict__ bias, const float* __restrict__ res,
    float* __restrict__ C, int M, int N, int K)
{
  __shared__ float As[16][68];  // pad 68: 16B-aligned rows, <=2-way banks
  __shared__ float Ws[16][68];
  const int tid = threadIdx.x;
  const int tx = tid & 15, ty = tid >> 4;
  const int m0 = blockIdx.y * 64, n0 = blockIdx.x * 64;
  const int lr = tid >> 2;         // 0..63 tile row
  const int lk = (tid & 3) * 4;    // 0,4,8,12 k offset
  float acc[4][4] = {};
  const float* Ap = A + (size_t)(m0 + lr) * K + lk;
  const float* Wp = W + (size_t)(n0 + lr) * K + lk;
  for (int k0 = 0; k0 < K; k0 += 16) {
    float4 av = *(const float4*)(Ap + k0);
    float4 wv = *(const float4*)(Wp + k0);
    __syncthreads();
    As[lk + 0][lr] = av.x; As[lk + 1][lr] = av.y;
    As[lk + 2][lr] = av.z; As[lk + 3][lr] = av.w;
    Ws[lk + 0][lr] = wv.x; Ws[lk + 1][lr] = wv.y;
    Ws[lk + 2][lr] = wv.z; Ws[lk + 3][lr] = wv.w;
    __syncthreads();
#pragma unroll
    for (int kk = 0; kk < 16; ++kk) {
      float4 a4 = *(const float4*)&As[kk][ty * 4];
      float4 b4 = *(const float4*)&Ws[kk][tx * 4];
      float a[4] = {a4.x, a4.y, a4.z, a4.w};
      float b[4] = {b4.x, b4.y, b4.z, b4.w};
#pragma unroll
      for (int i = 0; i < 4; ++i)
#pragma unroll
        for (int j = 0; j < 4; ++j) acc[i][j] += a[i] * b[j];
    }
  }
  float4 bv = *(const float4*)&bias[n0 + tx * 4];
#pragma unroll
  for (int i = 0; i < 4; ++i) {
    const int m = m0 + ty * 4 + i;
    float4 ov;
    ov.x = acc[i][0] + bv.x; ov.y = acc[i][1] + bv.y;
    ov.z = acc[i][2] + bv.z; ov.w = acc[i][3] + bv.w;
    if (ADD_RES) {
      float4 rv = *(const float4*)&res[(size_t)m * N + n0 + tx * 4];
      ov.x += rv.x; ov.y += rv.y; ov.z += rv.z; ov.w += rv.w;
    }
    *(float4*)&C[(size_t)m * N + n0 + tx * 4] = ov;
  }
}

// ---------------------------------------------------------------------------
// Rotary (per-token/head scalar phase) applied in-place to q,k; also emits
// cos/sin tables in [B,H,L] layout for the attention sync mask.
// One thread per (b,l,h,d) with d in [0,32): handles the (d, d+32) pair.
// ---------------------------------------------------------------------------
__global__ __launch_bounds__(256) void rotary_cs(
    float* __restrict__ q, float* __restrict__ k, const float* __restrict__ phi,
    float* __restrict__ cosp, float* __restrict__ sinp)
{
  const int idx = blockIdx.x * 256 + threadIdx.x;  // [0, B*L*H*32)
  const int d = idx & 31;
  const int h = (idx >> 5) & (HH - 1);
  const int l = (idx >> 9) & (LL - 1);
  const int b = idx >> 20;
  const float ph = phi[(b * LL + l) * HH + h];
  const float c = cosf(ph), s = sinf(ph);
  const size_t base = ((size_t)(b * LL + l) * HH + h) * HDD;
  const float q0 = q[base + d], q1 = q[base + d + 32];
  q[base + d]      = q0 * c - q1 * s;   // x1*c + (-x2)*s
  q[base + d + 32] = q1 * c + q0 * s;   // x2*c + ( x1)*s
  const float k0v = k[base + d], k1v = k[base + d + 32];
  k[base + d]      = k0v * c - k1v * s;
  k[base + d + 32] = k1v * c + k0v * s;
  if (d == 0) {
    cosp[(b * HH + h) * LL + l] = c;
    sinp[(b * HH + h) * LL + l] = s;
  }
}

// ---------------------------------------------------------------------------
// Flash-style attention with the behavioral sync mask.
// 1 thread = 1 query row; q[64],o[64] in registers; 32-key LDS tiles.
// All inner LDS reads are wave-uniform (broadcast, conflict-free).
// ---------------------------------------------------------------------------
__global__ __launch_bounds__(256) void attn(
    const float* __restrict__ Q, const float* __restrict__ K,
    const float* __restrict__ V, const float* __restrict__ cosp,
    const float* __restrict__ sinp, const float* __restrict__ am,
    float* __restrict__ ctx)
{
  __shared__ float Kt[32][64];
  __shared__ float Vt[32][64];
  __shared__ float cks[32], sks[32], ams[32];
  const int tid = threadIdx.x;
  const int bid = blockIdx.x;
  const int qt = bid & 7;                // L/256 = 8 query tiles
  const int h  = (bid >> 3) & (HH - 1);
  const int b  = bid >> 7;
  const int lq = qt * 256 + tid;

  const size_t qbase = ((size_t)(b * LL + lq) * HH + h) * HDD;
  float4 q4[16], o4[16];
#pragma unroll
  for (int i = 0; i < 16; ++i) q4[i] = *(const float4*)&Q[qbase + i * 4];
#pragma unroll
  for (int i = 0; i < 16; ++i) o4[i] = make_float4(0.f, 0.f, 0.f, 0.f);
  float mrow = -INFINITY, lrow = 0.f;
  const float cq = cosp[(b * HH + h) * LL + lq];
  const float sq = sinp[(b * HH + h) * LL + lq];

  const int jld = tid >> 3;            // 0..31 key row to load
  const int dld = (tid & 7) * 8;       // 0..56 dim offset

  for (int k0 = 0; k0 < LL; k0 += 32) {
    __syncthreads();
    {
      const size_t kb = ((size_t)(b * LL + k0 + jld) * HH + h) * HDD + dld;
      *(float4*)&Kt[jld][dld]     = *(const float4*)&K[kb];
      *(float4*)&Kt[jld][dld + 4] = *(const float4*)&K[kb + 4];
      *(float4*)&Vt[jld][dld]     = *(const float4*)&V[kb];
      *(float4*)&Vt[jld][dld + 4] = *(const float4*)&V[kb + 4];
      if (tid < 32) {
        cks[tid] = cosp[(b * HH + h) * LL + k0 + tid];
        sks[tid] = sinp[(b * HH + h) * LL + k0 + tid];
        ams[tid] = am[b * LL + k0 + tid];
      }
    }
    __syncthreads();
#pragma unroll
    for (int jc = 0; jc < 4; ++jc) {     // 8-key chunks amortize rescale
      float s[8];
#pragma unroll
      for (int jj = 0; jj < 8; ++jj) {
        const int j = jc * 8 + jj;
        float acc = 0.f;
#pragma unroll
        for (int d4 = 0; d4 < 16; ++d4) {
          float4 kv = *(const float4*)&Kt[j][d4 * 4];
          acc += q4[d4].x * kv.x + q4[d4].y * kv.y +
                 q4[d4].z * kv.z + q4[d4].w * kv.w;
        }
        float sc = acc * 0.125f;  // 1/sqrt(64)
        const bool msk = (cq * cks[j] + sq * sks[j] < -0.7f) && ((k0 + j) != lq);
        sc = msk ? -1e9f : sc;
        s[jj] = sc + ams[j];      // attention_mask added after sync mask (ref order)
      }
      float cm = s[0];
#pragma unroll
      for (int jj = 1; jj < 8; ++jj) cm = fmaxf(cm, s[jj]);
      const float mnew = fmaxf(mrow, cm);
      const float alpha = __expf(mrow - mnew);  // exp(-inf)=0 handles init
      mrow = mnew;
      lrow *= alpha;
#pragma unroll
      for (int i = 0; i < 16; ++i) {
        o4[i].x *= alpha; o4[i].y *= alpha; o4[i].z *= alpha; o4[i].w *= alpha;
      }
#pragma unroll
      for (int jj = 0; jj < 8; ++jj) {
        const int j = jc * 8 + jj;
        const float p = __expf(s[jj] - mnew);
        lrow += p;
#pragma unroll
        for (int d4 = 0; d4 < 16; ++d4) {
          float4 vv = *(const float4*)&Vt[j][d4 * 4];
          o4[d4].x += p * vv.x; o4[d4].y += p * vv.y;
          o4[d4].z += p * vv.z; o4[d4].w += p * vv.w;
        }
      }
    }
  }
  // all-masked edge case: softmax collapses to one-hot on the diagonal
  if (mrow <= -1e8f) {
#pragma unroll
    for (int i = 0; i < 16; ++i) o4[i] = *(const float4*)&V[qbase + i * 4];
    lrow = 1.f;
  }
  const float inv = 1.f / lrow;
  // ctx in [B,L,H,HD] == [B,L,D] (matches reference transpose+reshape)
#pragma unroll
  for (int i = 0; i < 16; ++i) {
    float4 ov = make_float4(o4[i].x * inv, o4[i].y * inv,
                            o4[i].z * inv, o4[i].w * inv);
    *(float4*)&ctx[qbase + i * 4] = ov;
  }
}

// ---------------------------------------------------------------------------
// LayerNorm over D=1024, one block per row.
// ---------------------------------------------------------------------------
__global__ __launch_bounds__(256) void layernorm(
    const float* __restrict__ x, const float* __restrict__ g,
    const float* __restrict__ bta, float* __restrict__ out)
{
  __shared__ float red[8];
  const int row = blockIdx.x;
  const int tid = threadIdx.x;
  const float* xr = x + (size_t)row * DD;
  float lsum = 0.f, lsq = 0.f;
  float v[4];
#pragma unroll
  for (int i = 0; i < 4; ++i) {
    v[i] = xr[tid + i * 256];
    lsum += v[i];
    lsq += v[i] * v[i];
  }
#pragma unroll
  for (int off = 32; off > 0; off >>= 1) {
    lsum += __shfl_down(lsum, off, 64);
    lsq  += __shfl_down(lsq,  off, 64);
  }
  const int wid = tid >> 6;
  if ((tid & 63) == 0) { red[wid] = lsum; red[wid + 4] = lsq; }
  __syncthreads();
  const float tsum = red[0] + red[1] + red[2] + red[3];
  const float tsq  = red[4] + red[5] + red[6] + red[7];
  const float mean = tsum * (1.f / DD);
  const float var  = tsq * (1.f / DD) - mean * mean;
  const float inv  = rsqrtf(var + 1e-12f);
#pragma unroll
  for (int i = 0; i < 4; ++i) {
    const int c = tid + i * 256;
    out[(size_t)row * DD + c] = (v[i] - mean) * inv * g[c] + bta[c];
  }
}

// ---------------------------------------------------------------------------
extern "C" void kernel_launch(void* const* d_in, const int* in_sizes, int n_in,
                              void* d_out, int out_size, void* d_ws, size_t ws_size,
                              hipStream_t stream)
{
  const float* hs  = (const float*)d_in[0];
  const float* amk = (const float*)d_in[1];
  const float* phi = (const float*)d_in[2];
  const float* Wq  = (const float*)d_in[3];
  const float* bq  = (const float*)d_in[4];
  const float* Wk  = (const float*)d_in[5];
  const float* bk  = (const float*)d_in[6];
  const float* Wv  = (const float*)d_in[7];
  const float* bv  = (const float*)d_in[8];
  const float* Wo  = (const float*)d_in[9];
  const float* bo  = (const float*)d_in[10];
  const float* lng = (const float*)d_in[11];
  const float* lnb = (const float*)d_in[12];
  float* out = (float*)d_out;

  float* ws = (float*)d_ws;
  const size_t SZ = (size_t)BB * LL * DD;  // 4194304
  float* qb   = ws;
  float* kb   = ws + SZ;
  float* vb   = ws + 2 * SZ;
  float* cbuf = ws + 3 * SZ;               // ctx
  float* cosp = ws + 4 * SZ;
  float* sinp = cosp + (size_t)BB * HH * LL;
  float* xb   = qb;                        // q dead after attention; reuse for x

  dim3 gg(DD / 64, (BB * LL) / 64);        // (16, 64)
  gemm_bt<false><<<gg, 256, 0, stream>>>(hs, Wq, bq, nullptr, qb, BB * LL, DD, DD);
  gemm_bt<false><<<gg, 256, 0, stream>>>(hs, Wk, bk, nullptr, kb, BB * LL, DD, DD);
  gemm_bt<false><<<gg, 256, 0, stream>>>(hs, Wv, bv, nullptr, vb, BB * LL, DD, DD);
  rotary_cs<<<(BB * LL * HH * 32) / 256, 256, 0, stream>>>(qb, kb, phi, cosp, sinp);
  attn<<<BB * HH * (LL / 256), 256, 0, stream>>>(qb, kb, vb, cosp, sinp, amk, cbuf);
  gemm_bt<true><<<gg, 256, 0, stream>>>(cbuf, Wo, bo, hs, xb, BB * LL, DD, DD);
  layernorm<<<BB * LL, 256, 0, stream>>>(xb, lng, lnb, out);
}

// Round 2
// 753.732 us; speedup vs baseline: 2.3447x; 2.3447x over previous
//
#include <hip/hip_runtime.h>
#include <cmath>

#define BB 2
#define LL 2048
#define DD 1024
#define HH 16
#define HDD 64

typedef _Float16 v8h __attribute__((ext_vector_type(8)));
typedef _Float16 v4h __attribute__((ext_vector_type(4)));
typedef float v4f __attribute__((ext_vector_type(4)));

// ---------------------------------------------------------------------------
// GEMM: C[M,N] = A[M,K] @ W[N,K]^T + bias[N] (+ res[M,N])  (fp32 baseline)
// ---------------------------------------------------------------------------
template <bool ADD_RES>
__global__ __launch_bounds__(256) void gemm_bt(
    const float* __restrict__ A, const float* __restrict__ W,
    const float* __restrict__ bias, const float* __restrict__ res,
    float* __restrict__ C, int M, int N, int K)
{
  __shared__ float As[16][68];
  __shared__ float Ws[16][68];
  const int tid = threadIdx.x;
  const int tx = tid & 15, ty = tid >> 4;
  const int m0 = blockIdx.y * 64, n0 = blockIdx.x * 64;
  const int lr = tid >> 2;
  const int lk = (tid & 3) * 4;
  float acc[4][4] = {};
  const float* Ap = A + (size_t)(m0 + lr) * K + lk;
  const float* Wp = W + (size_t)(n0 + lr) * K + lk;
  for (int k0 = 0; k0 < K; k0 += 16) {
    float4 av = *(const float4*)(Ap + k0);
    float4 wv = *(const float4*)(Wp + k0);
    __syncthreads();
    As[lk + 0][lr] = av.x; As[lk + 1][lr] = av.y;
    As[lk + 2][lr] = av.z; As[lk + 3][lr] = av.w;
    Ws[lk + 0][lr] = wv.x; Ws[lk + 1][lr] = wv.y;
    Ws[lk + 2][lr] = wv.z; Ws[lk + 3][lr] = wv.w;
    __syncthreads();
#pragma unroll
    for (int kk = 0; kk < 16; ++kk) {
      float4 a4 = *(const float4*)&As[kk][ty * 4];
      float4 b4 = *(const float4*)&Ws[kk][tx * 4];
      float a[4] = {a4.x, a4.y, a4.z, a4.w};
      float b[4] = {b4.x, b4.y, b4.z, b4.w};
#pragma unroll
      for (int i = 0; i < 4; ++i)
#pragma unroll
        for (int j = 0; j < 4; ++j) acc[i][j] += a[i] * b[j];
    }
  }
  float4 bv = *(const float4*)&bias[n0 + tx * 4];
#pragma unroll
  for (int i = 0; i < 4; ++i) {
    const int m = m0 + ty * 4 + i;
    float4 ov;
    ov.x = acc[i][0] + bv.x; ov.y = acc[i][1] + bv.y;
    ov.z = acc[i][2] + bv.z; ov.w = acc[i][3] + bv.w;
    if (ADD_RES) {
      float4 rv = *(const float4*)&res[(size_t)m * N + n0 + tx * 4];
      ov.x += rv.x; ov.y += rv.y; ov.z += rv.z; ov.w += rv.w;
    }
    *(float4*)&C[(size_t)m * N + n0 + tx * 4] = ov;
  }
}

// ---------------------------------------------------------------------------
// Rotary + cos/sin tables ([B,H,L] layout)
// ---------------------------------------------------------------------------
__global__ __launch_bounds__(256) void rotary_cs(
    float* __restrict__ q, float* __restrict__ k, const float* __restrict__ phi,
    float* __restrict__ cosp, float* __restrict__ sinp)
{
  const int idx = blockIdx.x * 256 + threadIdx.x;
  const int d = idx & 31;
  const int h = (idx >> 5) & (HH - 1);
  const int l = (idx >> 9) & (LL - 1);
  const int b = idx >> 20;
  const float ph = phi[(b * LL + l) * HH + h];
  const float c = cosf(ph), s = sinf(ph);
  const size_t base = ((size_t)(b * LL + l) * HH + h) * HDD;
  const float q0 = q[base + d], q1 = q[base + d + 32];
  q[base + d]      = q0 * c - q1 * s;
  q[base + d + 32] = q1 * c + q0 * s;
  const float k0v = k[base + d], k1v = k[base + d + 32];
  k[base + d]      = k0v * c - k1v * s;
  k[base + d + 32] = k1v * c + k0v * s;
  if (d == 0) {
    cosp[(b * HH + h) * LL + l] = c;
    sinp[(b * HH + h) * LL + l] = s;
  }
}

__device__ inline v8h cvt8(const float4& a, const float4& b, float sc) {
  v8h r;
  r[0] = (_Float16)(a.x * sc); r[1] = (_Float16)(a.y * sc);
  r[2] = (_Float16)(a.z * sc); r[3] = (_Float16)(a.w * sc);
  r[4] = (_Float16)(b.x * sc); r[5] = (_Float16)(b.y * sc);
  r[6] = (_Float16)(b.z * sc); r[7] = (_Float16)(b.w * sc);
  return r;
}

// ---------------------------------------------------------------------------
// MFMA flash attention with behavioral sync mask.
// Block: 4 waves, 128 queries (32/wave as 2x16). Key tiles of 64.
// S^T = K.Q^T via mfma_f32_16x16x32_f16 -> C-layout (key=quad*4+r, q=lane&15)
// == A-layout of mfma_f32_16x16x16f16 -> PV directly from registers.
// ---------------------------------------------------------------------------
__global__ __launch_bounds__(256) void attn_mfma(
    const float* __restrict__ Q, const float* __restrict__ K,
    const float* __restrict__ V, const float* __restrict__ cosp,
    const float* __restrict__ sinp, const float* __restrict__ am,
    float* __restrict__ ctx)
{
  __shared__ _Float16 Kt[64][72];   // [key][dim], +8 pad: uniform bank spread
  __shared__ _Float16 Vt[64][72];
  __shared__ float4 cs4[64];        // {cos, sin, attn_mask, 0} per key

  const int tid  = threadIdx.x;
  const int lane = tid & 63;
  const int wave = tid >> 6;
  const int quad = lane >> 4;
  const int ql   = lane & 15;
  const int bid  = blockIdx.x;      // 512 = B*H*(L/128)
  const int qt = bid & 15;
  const int h  = (bid >> 4) & 15;
  const int b  = bid >> 8;
  const int q0 = qt * 128 + wave * 32;
  const int csb = (b * HH + h) * LL;

  // Q fragments (scale 1/sqrt(64) folded in) + per-query cos/sin
  v8h qf[2][2];
  float cq[2], sq[2];
#pragma unroll
  for (int qs = 0; qs < 2; ++qs) {
    const int q = q0 + qs * 16 + ql;
    const float* qp = Q + ((size_t)((b * LL + q) * HH + h)) * HDD + quad * 8;
    float4 a = *(const float4*)qp;
    float4 b4 = *(const float4*)(qp + 4);
    float4 c = *(const float4*)(qp + 32);
    float4 d = *(const float4*)(qp + 36);
    qf[qs][0] = cvt8(a, b4, 0.125f);
    qf[qs][1] = cvt8(c, d, 0.125f);
    cq[qs] = cosp[csb + q];
    sq[qs] = sinp[csb + q];
  }

  v4f o[2][4];
#pragma unroll
  for (int qs = 0; qs < 2; ++qs)
#pragma unroll
    for (int nt = 0; nt < 4; ++nt) o[qs][nt] = (v4f){0.f, 0.f, 0.f, 0.f};
  float mrow[2] = {-INFINITY, -INFINITY};
  float lrow[2] = {0.f, 0.f};

  const int skey = tid >> 2;          // staging: key row
  const int sdof = (tid & 3) * 16;    // staging: dim offset

  for (int k0 = 0; k0 < LL; k0 += 64) {
    __syncthreads();
    {
      const size_t gb = ((size_t)((b * LL + k0 + skey) * HH + h)) * HDD + sdof;
      float4 ka = *(const float4*)&K[gb];
      float4 kb2 = *(const float4*)&K[gb + 4];
      float4 kc = *(const float4*)&K[gb + 8];
      float4 kd = *(const float4*)&K[gb + 12];
      *(v8h*)&Kt[skey][sdof]     = cvt8(ka, kb2, 1.f);
      *(v8h*)&Kt[skey][sdof + 8] = cvt8(kc, kd, 1.f);
      float4 va = *(const float4*)&V[gb];
      float4 vb = *(const float4*)&V[gb + 4];
      float4 vc = *(const float4*)&V[gb + 8];
      float4 vd = *(const float4*)&V[gb + 12];
      *(v8h*)&Vt[skey][sdof]     = cvt8(va, vb, 1.f);
      *(v8h*)&Vt[skey][sdof + 8] = cvt8(vc, vd, 1.f);
      if (tid < 64) {
        cs4[tid] = make_float4(cosp[csb + k0 + tid], sinp[csb + k0 + tid],
                               am[b * LL + k0 + tid], 0.f);
      }
    }
    __syncthreads();

    v4h pf[2][4];
    float alpha_[2];
#pragma unroll
    for (int qs = 0; qs < 2; ++qs) {
      // S^T tile: 4 chunks of 16 keys
      v4f st[4];
#pragma unroll
      for (int c = 0; c < 4; ++c) {
        v8h a0 = *(const v8h*)&Kt[c * 16 + ql][quad * 8];
        v8h a1 = *(const v8h*)&Kt[c * 16 + ql][32 + quad * 8];
        v4f z = (v4f){0.f, 0.f, 0.f, 0.f};
        z = __builtin_amdgcn_mfma_f32_16x16x32_f16(a0, qf[qs][0], z, 0, 0, 0);
        z = __builtin_amdgcn_mfma_f32_16x16x32_f16(a1, qf[qs][1], z, 0, 0, 0);
        st[c] = z;
      }
      // mask + tile max
      const int qglob = q0 + qs * 16 + ql;
      float s[16];
      float tm = -INFINITY;
#pragma unroll
      for (int c = 0; c < 4; ++c)
#pragma unroll
        for (int r = 0; r < 4; ++r) {
          const int kk = c * 16 + quad * 4 + r;
          float4 cs = cs4[kk];
          float sc = st[c][r];
          const bool msk = (cq[qs] * cs.x + sq[qs] * cs.y < -0.7f) &&
                           ((k0 + kk) != qglob);
          sc = msk ? -1e9f : sc;
          sc += cs.z;
          s[c * 4 + r] = sc;
          tm = fmaxf(tm, sc);
        }
      tm = fmaxf(tm, __shfl_xor(tm, 16, 64));
      tm = fmaxf(tm, __shfl_xor(tm, 32, 64));
      const float mnew = fmaxf(mrow[qs], tm);
      const float alpha = __expf(mrow[qs] - mnew);  // exp(-inf)=0 at init
      mrow[qs] = mnew;
      float lsum = 0.f;
#pragma unroll
      for (int i = 0; i < 16; ++i) { s[i] = __expf(s[i] - mnew); lsum += s[i]; }
      lsum += __shfl_xor(lsum, 16, 64);
      lsum += __shfl_xor(lsum, 32, 64);
      lrow[qs] = lrow[qs] * alpha + lsum;
#pragma unroll
      for (int c = 0; c < 4; ++c) {
        v4h t;
        t[0] = (_Float16)s[c * 4 + 0]; t[1] = (_Float16)s[c * 4 + 1];
        t[2] = (_Float16)s[c * 4 + 2]; t[3] = (_Float16)s[c * 4 + 3];
        pf[qs][c] = t;
      }
      alpha_[qs] = alpha;
    }
    // rescale O (alpha indexed by query=lane&15 -> remap to O rows quad*4+r)
#pragma unroll
    for (int qs = 0; qs < 2; ++qs) {
      const float a0 = __shfl(alpha_[qs], quad * 4 + 0, 64);
      const float a1 = __shfl(alpha_[qs], quad * 4 + 1, 64);
      const float a2 = __shfl(alpha_[qs], quad * 4 + 2, 64);
      const float a3 = __shfl(alpha_[qs], quad * 4 + 3, 64);
#pragma unroll
      for (int nt = 0; nt < 4; ++nt) {
        o[qs][nt][0] *= a0; o[qs][nt][1] *= a1;
        o[qs][nt][2] *= a2; o[qs][nt][3] *= a3;
      }
    }
    // PV: B-frags shared by both query sub-tiles
#pragma unroll
    for (int c = 0; c < 4; ++c) {
#pragma unroll
      for (int nt = 0; nt < 4; ++nt) {
        v4h vf;
        vf[0] = Vt[c * 16 + quad * 4 + 0][nt * 16 + ql];
        vf[1] = Vt[c * 16 + quad * 4 + 1][nt * 16 + ql];
        vf[2] = Vt[c * 16 + quad * 4 + 2][nt * 16 + ql];
        vf[3] = Vt[c * 16 + quad * 4 + 3][nt * 16 + ql];
        o[0][nt] = __builtin_amdgcn_mfma_f32_16x16x16f16(pf[0][c], vf, o[0][nt], 0, 0, 0);
        o[1][nt] = __builtin_amdgcn_mfma_f32_16x16x16f16(pf[1][c], vf, o[1][nt], 0, 0, 0);
      }
    }
  }

  // epilogue: normalize + write ctx [B,L,H,HD]
#pragma unroll
  for (int qs = 0; qs < 2; ++qs) {
    const float inv = 1.f / lrow[qs];
#pragma unroll
    for (int r = 0; r < 4; ++r) {
      const int q = q0 + qs * 16 + quad * 4 + r;
      const float ir = __shfl(inv, quad * 4 + r, 64);
      const float mr = __shfl(mrow[qs], quad * 4 + r, 64);
      const size_t ob = ((size_t)((b * LL + q) * HH + h)) * HDD + ql;
      if (mr <= -1e8f) {  // all-masked fallback (never taken with am=0)
        ctx[ob + 0]  = V[ob + 0];
        ctx[ob + 16] = V[ob + 16];
        ctx[ob + 32] = V[ob + 32];
        ctx[ob + 48] = V[ob + 48];
      } else {
        ctx[ob + 0]  = o[qs][0][r] * ir;
        ctx[ob + 16] = o[qs][1][r] * ir;
        ctx[ob + 32] = o[qs][2][r] * ir;
        ctx[ob + 48] = o[qs][3][r] * ir;
      }
    }
  }
}

// ---------------------------------------------------------------------------
// LayerNorm over D=1024
// ---------------------------------------------------------------------------
__global__ __launch_bounds__(256) void layernorm(
    const float* __restrict__ x, const float* __restrict__ g,
    const float* __restrict__ bta, float* __restrict__ out)
{
  __shared__ float red[8];
  const int row = blockIdx.x;
  const int tid = threadIdx.x;
  const float* xr = x + (size_t)row * DD;
  float lsum = 0.f, lsq = 0.f;
  float v[4];
#pragma unroll
  for (int i = 0; i < 4; ++i) {
    v[i] = xr[tid + i * 256];
    lsum += v[i];
    lsq += v[i] * v[i];
  }
#pragma unroll
  for (int off = 32; off > 0; off >>= 1) {
    lsum += __shfl_down(lsum, off, 64);
    lsq  += __shfl_down(lsq,  off, 64);
  }
  const int wid = tid >> 6;
  if ((tid & 63) == 0) { red[wid] = lsum; red[wid + 4] = lsq; }
  __syncthreads();
  const float tsum = red[0] + red[1] + red[2] + red[3];
  const float tsq  = red[4] + red[5] + red[6] + red[7];
  const float mean = tsum * (1.f / DD);
  const float var  = tsq * (1.f / DD) - mean * mean;
  const float inv  = rsqrtf(var + 1e-12f);
#pragma unroll
  for (int i = 0; i < 4; ++i) {
    const int c = tid + i * 256;
    out[(size_t)row * DD + c] = (v[i] - mean) * inv * g[c] + bta[c];
  }
}

// ---------------------------------------------------------------------------
extern "C" void kernel_launch(void* const* d_in, const int* in_sizes, int n_in,
                              void* d_out, int out_size, void* d_ws, size_t ws_size,
                              hipStream_t stream)
{
  const float* hs  = (const float*)d_in[0];
  const float* amk = (const float*)d_in[1];
  const float* phi = (const float*)d_in[2];
  const float* Wq  = (const float*)d_in[3];
  const float* bq  = (const float*)d_in[4];
  const float* Wk  = (const float*)d_in[5];
  const float* bk  = (const float*)d_in[6];
  const float* Wv  = (const float*)d_in[7];
  const float* bv  = (const float*)d_in[8];
  const float* Wo  = (const float*)d_in[9];
  const float* bo  = (const float*)d_in[10];
  const float* lng = (const float*)d_in[11];
  const float* lnb = (const float*)d_in[12];
  float* out = (float*)d_out;

  float* ws = (float*)d_ws;
  const size_t SZ = (size_t)BB * LL * DD;
  float* qb   = ws;
  float* kb   = ws + SZ;
  float* vb   = ws + 2 * SZ;
  float* cbuf = ws + 3 * SZ;
  float* cosp = ws + 4 * SZ;
  float* sinp = cosp + (size_t)BB * HH * LL;
  float* xb   = qb;

  dim3 gg(DD / 64, (BB * LL) / 64);
  gemm_bt<false><<<gg, 256, 0, stream>>>(hs, Wq, bq, nullptr, qb, BB * LL, DD, DD);
  gemm_bt<false><<<gg, 256, 0, stream>>>(hs, Wk, bk, nullptr, kb, BB * LL, DD, DD);
  gemm_bt<false><<<gg, 256, 0, stream>>>(hs, Wv, bv, nullptr, vb, BB * LL, DD, DD);
  rotary_cs<<<(BB * LL * HH * 32) / 256, 256, 0, stream>>>(qb, kb, phi, cosp, sinp);
  attn_mfma<<<BB * HH * (LL / 128), 256, 0, stream>>>(qb, kb, vb, cosp, sinp, amk, cbuf);
  gemm_bt<true><<<gg, 256, 0, stream>>>(cbuf, Wo, bo, hs, xb, BB * LL, DD, DD);
  layernorm<<<BB * LL, 256, 0, stream>>>(xb, lng, lnb, out);
}

// Round 3
// 320.324 us; speedup vs baseline: 5.5172x; 2.3530x over previous
//
#include <hip/hip_runtime.h>
#include <cmath>

#define BB 2
#define LL 2048
#define DD 1024
#define HH 16
#define HDD 64

typedef _Float16 v8h __attribute__((ext_vector_type(8)));
typedef _Float16 v4h __attribute__((ext_vector_type(4)));
typedef float v4f __attribute__((ext_vector_type(4)));

// async global->LDS, 16B per lane. LDS dest = wave-uniform base + lane*16.
#define GLD(gp, lp)                                                        \
  __builtin_amdgcn_global_load_lds(                                        \
      (const __attribute__((address_space(1))) void*)(gp),                 \
      (__attribute__((address_space(3))) void*)(lp), 16, 0, 0)

// ---------------------------------------------------------------------------
// fp32 -> f16 conversion: hs (1M float4) + Wq/Wk/Wv (into wqkvh) + Wo.
// ---------------------------------------------------------------------------
__global__ __launch_bounds__(256) void cvt_all(
    const float* __restrict__ hs, const float* __restrict__ wq,
    const float* __restrict__ wk, const float* __restrict__ wv,
    const float* __restrict__ wo, _Float16* __restrict__ hsh,
    _Float16* __restrict__ wqkvh, _Float16* __restrict__ woh)
{
  const int i = blockIdx.x * 256 + threadIdx.x;  // float4 units, total 2M
  const float* s;
  _Float16* d;
  if (i < 1048576)      { s = hs + (size_t)i * 4;            d = hsh + (size_t)i * 4; }
  else if (i < 1310720) { int j = i - 1048576; s = wq + (size_t)j * 4; d = wqkvh + (size_t)j * 4; }
  else if (i < 1572864) { int j = i - 1310720; s = wk + (size_t)j * 4; d = wqkvh + 1048576 + (size_t)j * 4; }
  else if (i < 1835008) { int j = i - 1572864; s = wv + (size_t)j * 4; d = wqkvh + 2097152 + (size_t)j * 4; }
  else                  { int j = i - 1835008; s = wo + (size_t)j * 4; d = woh + (size_t)j * 4; }
  float4 v = *(const float4*)s;
  v4h o;
  o[0] = (_Float16)v.x; o[1] = (_Float16)v.y;
  o[2] = (_Float16)v.z; o[3] = (_Float16)v.w;
  *(v4h*)d = o;
}

// ---------------------------------------------------------------------------
// m97-style MFMA GEMM core: 128x128 tile, BK=32, 256 thr (2x2 waves of 64x64).
// C[m][n] = sum_k A[m][k] * W[n][k].  A,W f16 row-major, acc fp32.
// ---------------------------------------------------------------------------
__device__ __forceinline__ void gemm_loop(
    const _Float16* __restrict__ A, const _Float16* __restrict__ W, const int K,
    const int m0, const int n0, const int tid, const int wave, const int lane,
    _Float16* As, _Float16* Bs, v4f acc[4][4])
{
  const int quad = lane >> 4;
  const int ql = lane & 15;
  const int wm = (wave >> 1) * 64;
  const int wn = (wave & 1) * 64;
  const int srow = tid >> 2;        // 0..63 staging row (inst0)
  const int skof = (tid & 3) * 8;   // k offset in f16
  const _Float16* Ap = A + (size_t)(m0 + srow) * K + skof;
  const _Float16* Wp = W + (size_t)(n0 + srow) * K + skof;
  const size_t rstep = (size_t)64 * K;
  for (int k0 = 0; k0 < K; k0 += 32) {
    __syncthreads();
    GLD(Ap + k0,         As + tid * 8);
    GLD(Ap + rstep + k0, As + 2048 + tid * 8);
    GLD(Wp + k0,         Bs + tid * 8);
    GLD(Wp + rstep + k0, Bs + 2048 + tid * 8);
    __syncthreads();
    v8h af[4], bf[4];
#pragma unroll
    for (int mt = 0; mt < 4; ++mt)
      af[mt] = *(const v8h*)&As[(wm + mt * 16 + ql) * 32 + quad * 8];
#pragma unroll
    for (int nt = 0; nt < 4; ++nt)
      bf[nt] = *(const v8h*)&Bs[(wn + nt * 16 + ql) * 32 + quad * 8];
#pragma unroll
    for (int mt = 0; mt < 4; ++mt)
#pragma unroll
      for (int nt = 0; nt < 4; ++nt)
        acc[mt][nt] = __builtin_amdgcn_mfma_f32_16x16x32_f16(
            af[mt], bf[nt], acc[mt][nt], 0, 0, 0);
  }
}

// QKV fused GEMM: N=3072; whole 128-block maps to one of q/k/v (1024-col bands)
__global__ __launch_bounds__(256) void gemm_qkv(
    const _Float16* __restrict__ A, const _Float16* __restrict__ W,
    const float* __restrict__ bq, const float* __restrict__ bk,
    const float* __restrict__ bv, _Float16* __restrict__ qh,
    _Float16* __restrict__ kh, _Float16* __restrict__ vh)
{
  __shared__ _Float16 As[128 * 32];
  __shared__ _Float16 Bs[128 * 32];
  const int tid = threadIdx.x, lane = tid & 63, wave = tid >> 6;
  const int quad = lane >> 4, ql = lane & 15;
  const int m0 = blockIdx.y * 128, n0 = blockIdx.x * 128;
  v4f acc[4][4];
#pragma unroll
  for (int mt = 0; mt < 4; ++mt)
#pragma unroll
    for (int nt = 0; nt < 4; ++nt) acc[mt][nt] = (v4f){0.f, 0.f, 0.f, 0.f};
  gemm_loop(A, W, DD, m0, n0, tid, wave, lane, As, Bs, acc);
  const int buf = n0 >> 10;
  _Float16* outp = buf == 0 ? qh : (buf == 1 ? kh : vh);
  const float* bias = buf == 0 ? bq : (buf == 1 ? bk : bv);
  const int nc0 = (n0 & 1023) + (wave & 1) * 64;
  const int mr0 = m0 + (wave >> 1) * 64;
#pragma unroll
  for (int nt = 0; nt < 4; ++nt) {
    const int col = nc0 + nt * 16 + ql;
    const float bb = bias[col];
#pragma unroll
    for (int mt = 0; mt < 4; ++mt)
#pragma unroll
      for (int r = 0; r < 4; ++r) {
        const int row = mr0 + mt * 16 + quad * 4 + r;
        outp[(size_t)row * DD + col] = (_Float16)(acc[mt][nt][r] + bb);
      }
  }
}

// O-proj GEMM: f16 A,W; fp32 bias + residual epilogue
__global__ __launch_bounds__(256) void gemm_o(
    const _Float16* __restrict__ A, const _Float16* __restrict__ W,
    const float* __restrict__ bo, const float* __restrict__ res,
    float* __restrict__ out)
{
  __shared__ _Float16 As[128 * 32];
  __shared__ _Float16 Bs[128 * 32];
  const int tid = threadIdx.x, lane = tid & 63, wave = tid >> 6;
  const int quad = lane >> 4, ql = lane & 15;
  const int m0 = blockIdx.y * 128, n0 = blockIdx.x * 128;
  v4f acc[4][4];
#pragma unroll
  for (int mt = 0; mt < 4; ++mt)
#pragma unroll
    for (int nt = 0; nt < 4; ++nt) acc[mt][nt] = (v4f){0.f, 0.f, 0.f, 0.f};
  gemm_loop(A, W, DD, m0, n0, tid, wave, lane, As, Bs, acc);
  const int nc0 = n0 + (wave & 1) * 64;
  const int mr0 = m0 + (wave >> 1) * 64;
#pragma unroll
  for (int nt = 0; nt < 4; ++nt) {
    const int col = nc0 + nt * 16 + ql;
    const float bb = bo[col];
#pragma unroll
    for (int mt = 0; mt < 4; ++mt)
#pragma unroll
      for (int r = 0; r < 4; ++r) {
        const int row = mr0 + mt * 16 + quad * 4 + r;
        const size_t ix = (size_t)row * DD + col;
        out[ix] = acc[mt][nt][r] + bb + res[ix];
      }
  }
}

// ---------------------------------------------------------------------------
// Rotary on f16 q,k + cos/sin tables ([B,H,L] fp32)
// ---------------------------------------------------------------------------
__global__ __launch_bounds__(256) void rotary_h(
    _Float16* __restrict__ q, _Float16* __restrict__ k,
    const float* __restrict__ phi, float* __restrict__ cosp,
    float* __restrict__ sinp)
{
  const int idx = blockIdx.x * 256 + threadIdx.x;
  const int d = idx & 31;
  const int h = (idx >> 5) & (HH - 1);
  const int l = (idx >> 9) & (LL - 1);
  const int b = idx >> 20;
  const float ph = phi[(b * LL + l) * HH + h];
  const float c = cosf(ph), s = sinf(ph);
  const size_t base = ((size_t)(b * LL + l) * HH + h) * HDD;
  const float q0 = (float)q[base + d], q1 = (float)q[base + d + 32];
  q[base + d]      = (_Float16)(q0 * c - q1 * s);
  q[base + d + 32] = (_Float16)(q1 * c + q0 * s);
  const float k0v = (float)k[base + d], k1v = (float)k[base + d + 32];
  k[base + d]      = (_Float16)(k0v * c - k1v * s);
  k[base + d + 32] = (_Float16)(k1v * c + k0v * s);
  if (d == 0) {
    cosp[(b * HH + h) * LL + l] = c;
    sinp[(b * HH + h) * LL + l] = s;
  }
}

__device__ __forceinline__ v8h scale8(v8h x) {
  v8h r;
#pragma unroll
  for (int i = 0; i < 8; ++i) r[i] = x[i] * (_Float16)0.125f;
  return r;
}

// ---------------------------------------------------------------------------
// MFMA flash attention, f16 Q/K/V, global_load_lds staging with XOR-swizzled
// 16B chunks (swizzle on the global source offset; LDS dest must stay
// lane-contiguous). chunk_stored = chunk_global ^ (row & 7).
// ---------------------------------------------------------------------------
__global__ __launch_bounds__(256) void attn_mfma(
    const _Float16* __restrict__ Q, const _Float16* __restrict__ K,
    const _Float16* __restrict__ V, const float* __restrict__ cosp,
    const float* __restrict__ sinp, const float* __restrict__ am,
    _Float16* __restrict__ ctx)
{
  __shared__ _Float16 Kt[64 * 64];
  __shared__ _Float16 Vt[64 * 64];
  __shared__ float4 cs4[64];

  const int tid  = threadIdx.x;
  const int lane = tid & 63;
  const int wave = tid >> 6;
  const int quad = lane >> 4;
  const int ql   = lane & 15;
  const int bid  = blockIdx.x;
  const int qt = bid & 15;
  const int h  = (bid >> 4) & 15;
  const int b  = bid >> 8;
  const int q0 = qt * 128 + wave * 32;
  const int csb = (b * HH + h) * LL;

  v8h qf[2][2];
  float cq[2], sq[2];
#pragma unroll
  for (int qs = 0; qs < 2; ++qs) {
    const int q = q0 + qs * 16 + ql;
    const _Float16* qp = Q + ((size_t)((b * LL + q) * HH + h)) * HDD + quad * 8;
    qf[qs][0] = scale8(*(const v8h*)qp);
    qf[qs][1] = scale8(*(const v8h*)(qp + 32));
    cq[qs] = cosp[csb + q];
    sq[qs] = sinp[csb + q];
  }

  v4f o[2][4];
#pragma unroll
  for (int qs = 0; qs < 2; ++qs)
#pragma unroll
    for (int nt = 0; nt < 4; ++nt) o[qs][nt] = (v4f){0.f, 0.f, 0.f, 0.f};
  float mrow[2] = {-INFINITY, -INFINITY};
  float lrow[2] = {0.f, 0.f};

  const int srow = tid >> 3;          // 0..31 staging row (inst0)
  const int sgc = (tid & 7) ^ (srow & 7);  // swizzled global chunk

  for (int k0 = 0; k0 < LL; k0 += 64) {
    __syncthreads();
    {
      const size_t kb = ((size_t)((b * LL + k0 + srow) * HH + h)) * HDD + sgc * 8;
      GLD(K + kb,             Kt + tid * 8);
      GLD(K + kb + 32 * 1024, Kt + 2048 + tid * 8);
      GLD(V + kb,             Vt + tid * 8);
      GLD(V + kb + 32 * 1024, Vt + 2048 + tid * 8);
      if (tid < 64) {
        cs4[tid] = make_float4(cosp[csb + k0 + tid], sinp[csb + k0 + tid],
                               am[b * LL + k0 + tid], 0.f);
      }
    }
    __syncthreads();

    v4h pf[2][4];
    float alpha_[2];
#pragma unroll
    for (int qs = 0; qs < 2; ++qs) {
      v4f st[4];
#pragma unroll
      for (int c = 0; c < 4; ++c) {
        const int krow = c * 16 + ql;
        const int sw = krow & 7;
        v8h a0 = *(const v8h*)&Kt[krow * 64 + ((quad ^ sw) << 3)];
        v8h a1 = *(const v8h*)&Kt[krow * 64 + (((quad + 4) ^ sw) << 3)];
        v4f z = (v4f){0.f, 0.f, 0.f, 0.f};
        z = __builtin_amdgcn_mfma_f32_16x16x32_f16(a0, qf[qs][0], z, 0, 0, 0);
        z = __builtin_amdgcn_mfma_f32_16x16x32_f16(a1, qf[qs][1], z, 0, 0, 0);
        st[c] = z;
      }
      const int qglob = q0 + qs * 16 + ql;
      float s[16];
      float tm = -INFINITY;
#pragma unroll
      for (int c = 0; c < 4; ++c)
#pragma unroll
        for (int r = 0; r < 4; ++r) {
          const int kk = c * 16 + quad * 4 + r;
          float4 cs = cs4[kk];
          float sc = st[c][r];
          const bool msk = (cq[qs] * cs.x + sq[qs] * cs.y < -0.7f) &&
                           ((k0 + kk) != qglob);
          sc = msk ? -1e9f : sc;
          sc += cs.z;
          s[c * 4 + r] = sc;
          tm = fmaxf(tm, sc);
        }
      tm = fmaxf(tm, __shfl_xor(tm, 16, 64));
      tm = fmaxf(tm, __shfl_xor(tm, 32, 64));
      const float mnew = fmaxf(mrow[qs], tm);
      const float alpha = __expf(mrow[qs] - mnew);
      mrow[qs] = mnew;
      float lsum = 0.f;
#pragma unroll
      for (int i = 0; i < 16; ++i) { s[i] = __expf(s[i] - mnew); lsum += s[i]; }
      lsum += __shfl_xor(lsum, 16, 64);
      lsum += __shfl_xor(lsum, 32, 64);
      lrow[qs] = lrow[qs] * alpha + lsum;
#pragma unroll
      for (int c = 0; c < 4; ++c) {
        v4h t;
        t[0] = (_Float16)s[c * 4 + 0]; t[1] = (_Float16)s[c * 4 + 1];
        t[2] = (_Float16)s[c * 4 + 2]; t[3] = (_Float16)s[c * 4 + 3];
        pf[qs][c] = t;
      }
      alpha_[qs] = alpha;
    }
#pragma unroll
    for (int qs = 0; qs < 2; ++qs) {
      const float a0 = __shfl(alpha_[qs], quad * 4 + 0, 64);
      const float a1 = __shfl(alpha_[qs], quad * 4 + 1, 64);
      const float a2 = __shfl(alpha_[qs], quad * 4 + 2, 64);
      const float a3 = __shfl(alpha_[qs], quad * 4 + 3, 64);
#pragma unroll
      for (int nt = 0; nt < 4; ++nt) {
        o[qs][nt][0] *= a0; o[qs][nt][1] *= a1;
        o[qs][nt][2] *= a2; o[qs][nt][3] *= a3;
      }
    }
#pragma unroll
    for (int c = 0; c < 4; ++c) {
#pragma unroll
      for (int nt = 0; nt < 4; ++nt) {
        v4h vf;
#pragma unroll
        for (int j = 0; j < 4; ++j) {
          const int vrow = c * 16 + quad * 4 + j;
          const int gc = nt * 2 + (ql >> 3);
          vf[j] = Vt[vrow * 64 + ((gc ^ (vrow & 7)) << 3) + (ql & 7)];
        }
        o[0][nt] = __builtin_amdgcn_mfma_f32_16x16x16f16(pf[0][c], vf, o[0][nt], 0, 0, 0);
        o[1][nt] = __builtin_amdgcn_mfma_f32_16x16x16f16(pf[1][c], vf, o[1][nt], 0, 0, 0);
      }
    }
  }

#pragma unroll
  for (int qs = 0; qs < 2; ++qs) {
    const float inv = 1.f / lrow[qs];
#pragma unroll
    for (int r = 0; r < 4; ++r) {
      const int q = q0 + qs * 16 + quad * 4 + r;
      const float ir = __shfl(inv, quad * 4 + r, 64);
      const float mr = __shfl(mrow[qs], quad * 4 + r, 64);
      const size_t ob = ((size_t)((b * LL + q) * HH + h)) * HDD + ql;
      if (mr <= -1e8f) {
        ctx[ob + 0]  = V[ob + 0];
        ctx[ob + 16] = V[ob + 16];
        ctx[ob + 32] = V[ob + 32];
        ctx[ob + 48] = V[ob + 48];
      } else {
        ctx[ob + 0]  = (_Float16)(o[qs][0][r] * ir);
        ctx[ob + 16] = (_Float16)(o[qs][1][r] * ir);
        ctx[ob + 32] = (_Float16)(o[qs][2][r] * ir);
        ctx[ob + 48] = (_Float16)(o[qs][3][r] * ir);
      }
    }
  }
}

// ---------------------------------------------------------------------------
// LayerNorm over D=1024
// ---------------------------------------------------------------------------
__global__ __launch_bounds__(256) void layernorm(
    const float* __restrict__ x, const float* __restrict__ g,
    const float* __restrict__ bta, float* __restrict__ out)
{
  __shared__ float red[8];
  const int row = blockIdx.x;
  const int tid = threadIdx.x;
  const float* xr = x + (size_t)row * DD;
  float lsum = 0.f, lsq = 0.f;
  float v[4];
#pragma unroll
  for (int i = 0; i < 4; ++i) {
    v[i] = xr[tid + i * 256];
    lsum += v[i];
    lsq += v[i] * v[i];
  }
#pragma unroll
  for (int off = 32; off > 0; off >>= 1) {
    lsum += __shfl_down(lsum, off, 64);
    lsq  += __shfl_down(lsq,  off, 64);
  }
  const int wid = tid >> 6;
  if ((tid & 63) == 0) { red[wid] = lsum; red[wid + 4] = lsq; }
  __syncthreads();
  const float tsum = red[0] + red[1] + red[2] + red[3];
  const float tsq  = red[4] + red[5] + red[6] + red[7];
  const float mean = tsum * (1.f / DD);
  const float var  = tsq * (1.f / DD) - mean * mean;
  const float inv  = rsqrtf(var + 1e-12f);
#pragma unroll
  for (int i = 0; i < 4; ++i) {
    const int c = tid + i * 256;
    out[(size_t)row * DD + c] = (v[i] - mean) * inv * g[c] + bta[c];
  }
}

// ---------------------------------------------------------------------------
extern "C" void kernel_launch(void* const* d_in, const int* in_sizes, int n_in,
                              void* d_out, int out_size, void* d_ws, size_t ws_size,
                              hipStream_t stream)
{
  const float* hs  = (const float*)d_in[0];
  const float* amk = (const float*)d_in[1];
  const float* phi = (const float*)d_in[2];
  const float* Wq  = (const float*)d_in[3];
  const float* bq  = (const float*)d_in[4];
  const float* Wk  = (const float*)d_in[5];
  const float* bk  = (const float*)d_in[6];
  const float* Wv  = (const float*)d_in[7];
  const float* bv  = (const float*)d_in[8];
  const float* Wo  = (const float*)d_in[9];
  const float* bo  = (const float*)d_in[10];
  const float* lng = (const float*)d_in[11];
  const float* lnb = (const float*)d_in[12];
  float* out = (float*)d_out;

  const size_t SZ = (size_t)BB * LL * DD;   // 4 M elements
  _Float16* hsh   = (_Float16*)d_ws;
  _Float16* qh    = hsh + SZ;
  _Float16* kh    = qh + SZ;
  _Float16* vh    = kh + SZ;
  _Float16* ctxh  = vh + SZ;
  _Float16* wqkvh = ctxh + SZ;              // 3 M
  _Float16* woh   = wqkvh + 3 * (size_t)DD * DD;  // 1 M
  float* xb   = (float*)(woh + (size_t)DD * DD);
  float* cosp = xb + SZ;
  float* sinp = cosp + (size_t)BB * HH * LL;

  cvt_all<<<8192, 256, 0, stream>>>(hs, Wq, Wk, Wv, Wo, hsh, wqkvh, woh);
  gemm_qkv<<<dim3(24, 32), 256, 0, stream>>>(hsh, wqkvh, bq, bk, bv, qh, kh, vh);
  rotary_h<<<8192, 256, 0, stream>>>(qh, kh, phi, cosp, sinp);
  attn_mfma<<<BB * HH * (LL / 128), 256, 0, stream>>>(qh, kh, vh, cosp, sinp, amk, ctxh);
  gemm_o<<<dim3(8, 32), 256, 0, stream>>>(ctxh, woh, bo, hs, xb);
  layernorm<<<BB * LL, 256, 0, stream>>>(xb, lng, lnb, out);
}